// Round 5
// baseline (18.253 us; speedup 1.0000x reference)
//
#include <hip/hip_runtime.h>

#define N 8192
#define NT 1024
#define KPT 8                     // keys per thread
#define RPB 32                    // rows per block -> grid = 256 (1 block/CU)
#define KLOG2E 0.7213475108f      // 0.5 * log2(e)

// Branchless atan2, max err ~1.4e-6 rad (output slack is 7.9e-2).
__device__ __forceinline__ float fast_atan2f(float y, float x) {
    float ax = fabsf(x), ay = fabsf(y);
    float mx = fmaxf(ax, ay), mn = fminf(ax, ay);
    float r = mn * __builtin_amdgcn_rcpf(mx);
    float s = r * r;
    float p = fmaf(s, -0.01172120f, 0.05265332f);
    p = fmaf(s, p, -0.11643287f);
    p = fmaf(s, p, 0.19354346f);
    p = fmaf(s, p, -0.33262347f);
    p = fmaf(s, p, 0.99997726f);
    p = p * r;                                   // atan(mn/mx) in [0, pi/4]
    p = (ay > ax) ? (1.5707963268f - p) : p;
    p = (x < 0.f) ? (3.1415926536f - p) : p;
    p = copysignf(p, y);
    return (mx == 0.f) ? 0.f : p;
}

// ---------------------------------------------------------------------------
// One fused kernel, 256 blocks x 1024 threads (16 waves, 4/SIMD).
// Factorized softmax weights: exp(0.5(li-lj)^2) = 2^(K li^2) * 2^(K lj^2
// - 2K li lj); the per-row factor cancels in a/e, so per pair we compute only
//   w~ = exp2( fma(B_r, lj, C_j) ),  B_r = -2K li,  C_j = K lj^2
// (exponents bounded by +-K*lmax^2 ~ +-13: no over/underflow, no max pass).
// Masked keys (l < t) have true weight exactly 0 -> compacted away in LDS.
// Phase 4: 16 waves = 4 row-groups x 4 key-quarters; 8 rows share every
// ds_read_b128 (2 keys), per-quarter partials combined through LDS.
// ---------------------------------------------------------------------------
__global__ __launch_bounds__(NT) void sofa_kernel(const float* __restrict__ x,
                                                  float2* __restrict__ out) {
    __shared__ float2 keys[N];        // 64 KiB worst case
    __shared__ float2 wred[16];
    __shared__ int    wcnt[16];
    __shared__ float  rowl[RPB];
    __shared__ float2 pred[16][8];    // per-wave row partials {e, a}
    __shared__ float  tc[1];          // threshold t

    const int tid  = threadIdx.x;
    const int lane = tid & 63, wave = tid >> 6;
    const int rowbase = blockIdx.x * RPB;

    // ---- phase 1: load x as float4 (2 keys each), compute l --------------
    float4 xq[4]; float l[KPT];
#pragma unroll
    for (int k = 0; k < 4; ++k)
        xq[k] = reinterpret_cast<const float4*>(x)[tid + k * NT];
#pragma unroll
    for (int k = 0; k < 4; ++k) {
        l[2 * k]     = sqrtf(xq[k].x * xq[k].x + xq[k].y * xq[k].y);
        l[2 * k + 1] = sqrtf(xq[k].z * xq[k].z + xq[k].w * xq[k].w);
    }
#pragma unroll
    for (int k = 0; k < 4; ++k) {
#pragma unroll
        for (int j = 0; j < 2; ++j) {
            int rel = 2 * (tid + k * NT) + j - rowbase;
            if ((unsigned)rel < (unsigned)RPB) rowl[rel] = l[2 * k + j];
        }
    }

    // ---- phase 2: stats -> t = mean + 0.1*std(ddof=1) --------------------
    float s = 0.f, s2 = 0.f;
#pragma unroll
    for (int k = 0; k < KPT; ++k) { s += l[k]; s2 += l[k] * l[k]; }
#pragma unroll
    for (int o = 32; o > 0; o >>= 1) {
        s  += __shfl_xor(s, o, 64);
        s2 += __shfl_xor(s2, o, 64);
    }
    if (lane == 0) wred[wave] = make_float2(s, s2);
    __syncthreads();
    if (tid == 0) {
        double S = 0.0, S2 = 0.0;
        for (int i = 0; i < 16; ++i) { S += (double)wred[i].x; S2 += (double)wred[i].y; }
        double mean = S / (double)N;
        double var  = (S2 - S * S / (double)N) / (double)(N - 1);
        tc[0] = (float)(mean + 0.1 * sqrt(var));
    }
    __syncthreads();
    const float t = tc[0];

    // ---- phase 3: flags + block scan + compact to LDS --------------------
    bool f[KPT]; int cnt = 0;
#pragma unroll
    for (int k = 0; k < KPT; ++k) { f[k] = (l[k] >= t); cnt += f[k] ? 1 : 0; }
    int inc = cnt;
#pragma unroll
    for (int o = 1; o < 64; o <<= 1) {
        int v = __shfl_up(inc, o, 64);
        if (lane >= o) inc += v;
    }
    if (lane == 63) wcnt[wave] = inc;
    __syncthreads();
    int wbase = 0, M = 0;
#pragma unroll
    for (int i = 0; i < 16; ++i) { int c = wcnt[i]; if (i < wave) wbase += c; M += c; }
    int pos = wbase + inc - cnt;
    const bool all = (M == 0);        // degenerate: -1e9 everywhere cancels
    if (all) { pos = tid * KPT; M = N; }
#pragma unroll
    for (int k = 0; k < 4; ++k) {
        if (f[2 * k] | all)
            keys[pos++] = make_float2(l[2 * k], fast_atan2f(xq[k].y, xq[k].x));
        if (f[2 * k + 1] | all)
            keys[pos++] = make_float2(l[2 * k + 1], fast_atan2f(xq[k].w, xq[k].z));
    }
    const int Mpad = (M + 511) & ~511;
    const int npad = Mpad - M;
    if (tid < npad) keys[M + tid] = make_float2(t, 0.f);
    __syncthreads();

    // ---- phase 4: 4 key-quarters x 4 row-groups; 8 rows share each b128 --
    const int q = wave & 3, rg = wave >> 2;
    const int P  = Mpad >> 1;         // float4 count, multiple of 256
    const int Pq = P >> 2;            // per-quarter, multiple of 64
    const int base = q * Pq;
    const float4* kk = reinterpret_cast<const float4*>(keys);

    float li8[8], B8[8];
#pragma unroll
    for (int r = 0; r < 8; ++r) {
        li8[r] = rowl[rg * 8 + r];
        B8[r]  = -2.f * KLOG2E * li8[r];
    }
    float ea0[8] = {}, ea1[8] = {}, aa0[8] = {}, aa1[8] = {};
#pragma unroll 2
    for (int p = base + lane; p < base + Pq; p += 64) {
        float4 v = kk[p];             // keys 2p, 2p+1: {l0,a0,l1,a1}
        float C0 = (v.x * KLOG2E) * v.x;
        float C1 = (v.z * KLOG2E) * v.z;
#pragma unroll
        for (int r = 0; r < 8; ++r) {
            float w0 = __builtin_amdgcn_exp2f(fmaf(B8[r], v.x, C0));
            ea0[r] += w0; aa0[r] = fmaf(w0, v.y, aa0[r]);
            float w1 = __builtin_amdgcn_exp2f(fmaf(B8[r], v.z, C1));
            ea1[r] += w1; aa1[r] = fmaf(w1, v.w, aa1[r]);
        }
    }
#pragma unroll
    for (int r = 0; r < 8; ++r) {
        float e = ea0[r] + ea1[r], a = aa0[r] + aa1[r];
#pragma unroll
        for (int o = 32; o > 0; o >>= 1) {
            e += __shfl_xor(e, o, 64);
            a += __shfl_xor(a, o, 64);
        }
        if (lane == 0) pred[wave][r] = make_float2(e, a);
    }
    __syncthreads();

    // ---- epilogue: combine quarters, sentinel fix, write -----------------
    if (tid < RPB) {
        int rg2 = tid >> 3, rl = tid & 7;
        float e = 0.f, a = 0.f;
#pragma unroll
        for (int qq = 0; qq < 4; ++qq) {
            float2 pr = pred[rg2 * 4 + qq][rl];
            e += pr.x; a += pr.y;
        }
        float li = rowl[tid];
        if (npad) {   // sentinel keys {l=t, angle=0} contribute only to e
            float B = -2.f * KLOG2E * li;
            e -= (float)npad * __builtin_amdgcn_exp2f(fmaf(B, t, (t * KLOG2E) * t));
        }
        float oa = a / e;
        out[rowbase + tid] = make_float2(li * cosf(oa), li * sinf(oa));
    }
}

// ---------------------------------------------------------------------------
extern "C" void kernel_launch(void* const* d_in, const int* in_sizes, int n_in,
                              void* d_out, int out_size, void* d_ws, size_t ws_size,
                              hipStream_t stream) {
    const float* x = (const float*)d_in[0];
    sofa_kernel<<<N / RPB, NT, 0, stream>>>(x, (float2*)d_out);
}

// Round 6
// 16.921 us; speedup vs baseline: 1.0787x; 1.0787x over previous
//
#include <hip/hip_runtime.h>

#define N 8192
#define NT 1024
#define KPT (N / NT)              // 8 keys per thread
#define RPB 32                    // rows per block -> grid = 256
#define KLOG2E 0.7213475108f      // 0.5 * log2(e)

// Branchless atan2, max err ~1.4e-6 rad (output slack is 7.9e-2).
__device__ __forceinline__ float fast_atan2f(float y, float x) {
    float ax = fabsf(x), ay = fabsf(y);
    float mx = fmaxf(ax, ay), mn = fminf(ax, ay);
    float r = mn * __builtin_amdgcn_rcpf(mx);
    float s = r * r;
    float p = fmaf(s, -0.01172120f, 0.05265332f);
    p = fmaf(s, p, -0.11643287f);
    p = fmaf(s, p, 0.19354346f);
    p = fmaf(s, p, -0.33262347f);
    p = fmaf(s, p, 0.99997726f);
    p = p * r;                                   // atan(mn/mx) in [0, pi/4]
    p = (ay > ax) ? (1.5707963268f - p) : p;
    p = (x < 0.f) ? (3.1415926536f - p) : p;
    p = copysignf(p, y);
    return (mx == 0.f) ? 0.f : p;
}

// ---------------------------------------------------------------------------
// One fused kernel, 256 blocks x 1024 threads (16 waves, 4/SIMD).
// REVERT to round-4 structure: 2 key-halves x 8 row-groups, 4 rows share
// each ds_read_b128. (Round-5's 8-row sharing doubled accumulator state and
// regressed 16.8 -> 18.3 us; the trans pipe, not LDS issue, is binding.)
// Factorized softmax weights: exp(0.5(li-lj)^2) = 2^(K li^2) * 2^(K lj^2
// - 2K li lj); the per-row factor cancels in a/e, so per pair we compute only
//   w~ = exp2( fma(B_r, lj, C_j) ),  B_r = -2K li,  C_j = K lj^2
// (exponents bounded by +-K*lmax^2 ~ +-13: no over/underflow, no max pass).
// Masked keys (l < t) have true weight exactly 0 -> compacted away in LDS.
// ---------------------------------------------------------------------------
__global__ __launch_bounds__(NT) void sofa_kernel(const float* __restrict__ x,
                                                  float2* __restrict__ out) {
    __shared__ float2 keys[N];        // 64 KiB worst case
    __shared__ float2 wred[16];
    __shared__ int    wcnt[16];
    __shared__ float  rowl[RPB];
    __shared__ float2 pred[16][4];    // per-wave row partials {e, a}
    __shared__ float  tc[1];          // threshold t

    const int tid  = threadIdx.x;
    const int lane = tid & 63, wave = tid >> 6;
    const int rowbase = blockIdx.x * RPB;

    // ---- phase 1: load x, compute l --------------------------------------
    float2 xv[KPT]; float l[KPT];
#pragma unroll
    for (int k = 0; k < KPT; ++k)
        xv[k] = reinterpret_cast<const float2*>(x)[tid + k * NT];
#pragma unroll
    for (int k = 0; k < KPT; ++k)
        l[k] = sqrtf(xv[k].x * xv[k].x + xv[k].y * xv[k].y);
#pragma unroll
    for (int k = 0; k < KPT; ++k) {
        int rel = tid + k * NT - rowbase;
        if ((unsigned)rel < (unsigned)RPB) rowl[rel] = l[k];
    }

    // ---- phase 2: stats -> t = mean + 0.1*std(ddof=1) --------------------
    float s = 0.f, s2 = 0.f;
#pragma unroll
    for (int k = 0; k < KPT; ++k) { s += l[k]; s2 += l[k] * l[k]; }
#pragma unroll
    for (int o = 32; o > 0; o >>= 1) {
        s  += __shfl_xor(s, o, 64);
        s2 += __shfl_xor(s2, o, 64);
    }
    if (lane == 0) wred[wave] = make_float2(s, s2);
    __syncthreads();
    if (tid == 0) {
        double S = 0.0, S2 = 0.0;
        for (int i = 0; i < 16; ++i) { S += (double)wred[i].x; S2 += (double)wred[i].y; }
        double mean = S / (double)N;
        double var  = (S2 - S * S / (double)N) / (double)(N - 1);
        tc[0] = (float)(mean + 0.1 * sqrt(var));
    }
    __syncthreads();
    const float t = tc[0];

    // ---- phase 3: flags + block scan + compact to LDS --------------------
    bool f[KPT]; int cnt = 0;
#pragma unroll
    for (int k = 0; k < KPT; ++k) { f[k] = (l[k] >= t); cnt += f[k] ? 1 : 0; }
    int inc = cnt;
#pragma unroll
    for (int o = 1; o < 64; o <<= 1) {
        int v = __shfl_up(inc, o, 64);
        if (lane >= o) inc += v;
    }
    if (lane == 63) wcnt[wave] = inc;
    __syncthreads();
    int wbase = 0, M = 0;
#pragma unroll
    for (int i = 0; i < 16; ++i) { int c = wcnt[i]; if (i < wave) wbase += c; M += c; }
    int pos = wbase + inc - cnt;
    const bool all = (M == 0);        // degenerate: -1e9 everywhere cancels
    if (all) { pos = tid * KPT; M = N; }
#pragma unroll
    for (int k = 0; k < KPT; ++k)
        if (f[k] | all) keys[pos++] = make_float2(l[k], fast_atan2f(xv[k].y, xv[k].x));
    const int Mpad = (M + 255) & ~255;
    const int npad = Mpad - M;
    if (tid < npad) keys[M + tid] = make_float2(t, 0.f);
    __syncthreads();

    // ---- phase 4: stream; wave-half splits keys, 4 rows share each b128 --
    const int half = wave >> 3, rg = wave & 7;
    const int P = Mpad >> 1;          // float4 count, multiple of 128
    const int Ph = P >> 1;            // per-half, multiple of 64 -> balanced
    const int base = half * Ph;
    const float4* kk = reinterpret_cast<const float4*>(keys);

    float li4[4], B4[4];
#pragma unroll
    for (int r = 0; r < 4; ++r) {
        li4[r] = rowl[rg * 4 + r];
        B4[r]  = -2.f * KLOG2E * li4[r];
    }
    float ea[4][2] = {}, aa[4][2] = {};
#pragma unroll 2
    for (int p = base + lane; p < base + Ph; p += 64) {
        float4 v = kk[p];             // keys 2p, 2p+1: {l0,a0,l1,a1}
        float C0 = (v.x * KLOG2E) * v.x;
        float C1 = (v.z * KLOG2E) * v.z;
#pragma unroll
        for (int r = 0; r < 4; ++r) {
            float w0 = __builtin_amdgcn_exp2f(fmaf(B4[r], v.x, C0));
            ea[r][0] += w0; aa[r][0] = fmaf(w0, v.y, aa[r][0]);
            float w1 = __builtin_amdgcn_exp2f(fmaf(B4[r], v.z, C1));
            ea[r][1] += w1; aa[r][1] = fmaf(w1, v.w, aa[r][1]);
        }
    }
#pragma unroll
    for (int r = 0; r < 4; ++r) {
        float e = ea[r][0] + ea[r][1], a = aa[r][0] + aa[r][1];
#pragma unroll
        for (int o = 32; o > 0; o >>= 1) {
            e += __shfl_xor(e, o, 64);
            a += __shfl_xor(a, o, 64);
        }
        if (lane == 0) pred[wave][r] = make_float2(e, a);
    }
    __syncthreads();

    // ---- epilogue: combine halves, sentinel fix, write -------------------
    if (tid < RPB) {
        int rg2 = tid >> 2, r2 = tid & 3;
        float e = pred[rg2][r2].x + pred[rg2 + 8][r2].x;
        float a = pred[rg2][r2].y + pred[rg2 + 8][r2].y;
        float li = rowl[tid];
        if (npad) {   // sentinel keys {l=t, angle=0} contribute only to e
            float B = -2.f * KLOG2E * li;
            e -= (float)npad * __builtin_amdgcn_exp2f(fmaf(B, t, (t * KLOG2E) * t));
        }
        float oa = a / e;
        out[rowbase + tid] = make_float2(li * cosf(oa), li * sinf(oa));
    }
}

// ---------------------------------------------------------------------------
extern "C" void kernel_launch(void* const* d_in, const int* in_sizes, int n_in,
                              void* d_out, int out_size, void* d_ws, size_t ws_size,
                              hipStream_t stream) {
    const float* x = (const float*)d_in[0];
    sofa_kernel<<<N / RPB, NT, 0, stream>>>(x, (float2*)d_out);
}